// Round 1
// 11141.369 us; speedup vs baseline: 1.1682x; 1.1682x over previous
//
#include <hip/hip_runtime.h>
#include <hip/hip_bf16.h>

#define T_STEPS 4096
#define HID 2048
#define EMB 512
#define NCH 256

typedef unsigned long long u64;
typedef unsigned int u32;

__device__ __forceinline__ float sigm_f(float x) {
    x = fminf(fmaxf(x, -30.f), 30.f);
    return 1.f / (1.f + __expf(-x));
}
__device__ __forceinline__ float tanh_f(float x) {
    float ax = fminf(fabsf(x), 15.f);
    float e = __expf(2.f * ax);
    float t = (e - 1.f) / (e + 1.f);
    return copysignf(t, x);
}

// A1: per-char input projection P[c][j][g] = b_g[j] + emb[c]·Wg[0:512][j]
__global__ __launch_bounds__(256) void a1_proj(
    const float* __restrict__ emb,
    const float* __restrict__ Wf, const float* __restrict__ bf,
    const float* __restrict__ Wi, const float* __restrict__ bi,
    const float* __restrict__ Wo, const float* __restrict__ bo,
    const float* __restrict__ Wc, const float* __restrict__ bc,
    float* __restrict__ P) {
    const int g = blockIdx.x & 3;
    const int c0 = (blockIdx.x >> 2) << 3;
    const float* W = (g == 0) ? Wf : (g == 1) ? Wi : (g == 2) ? Wo : Wc;
    const float* b = (g == 0) ? bf : (g == 1) ? bi : (g == 2) ? bo : bc;
    __shared__ float el[8][EMB];
    const int tid = threadIdx.x;
    for (int q = tid; q < 8 * EMB; q += 256)
        el[q >> 9][q & 511] = emb[(size_t)(c0 + (q >> 9)) * EMB + (q & 511)];
    __syncthreads();
    float acc[8][8];
#pragma unroll
    for (int cc = 0; cc < 8; ++cc)
#pragma unroll
        for (int k = 0; k < 8; ++k) acc[cc][k] = 0.f;
    for (int e = 0; e < EMB; ++e) {
        float w8[8];
#pragma unroll
        for (int k = 0; k < 8; ++k) w8[k] = W[(size_t)e * HID + tid + (k << 8)];
#pragma unroll
        for (int cc = 0; cc < 8; ++cc) {
            float xe = el[cc][e];
#pragma unroll
            for (int k = 0; k < 8; ++k) acc[cc][k] = fmaf(xe, w8[k], acc[cc][k]);
        }
    }
    float bb[8];
#pragma unroll
    for (int k = 0; k < 8; ++k) bb[k] = b[tid + (k << 8)];
#pragma unroll
    for (int cc = 0; cc < 8; ++cc)
#pragma unroll
        for (int k = 0; k < 8; ++k)
            P[((((size_t)(c0 + cc) << 11) + tid + (k << 8)) << 2) + g] = acc[cc][k] + bb[k];
}

// A2: transpose recurrent weights -> WT[g][j][k] (k contiguous)
__global__ void a2_transpose(const float* __restrict__ Wf, const float* __restrict__ Wi,
                             const float* __restrict__ Wo, const float* __restrict__ Wc,
                             float* __restrict__ WT) {
    __shared__ float tile[32][33];
    const int g = blockIdx.z;
    const float* W = (g == 0) ? Wf : (g == 1) ? Wi : (g == 2) ? Wo : Wc;
    const int k0 = blockIdx.x << 5, j0 = blockIdx.y << 5;
    const int tx = threadIdx.x, ty = threadIdx.y;
#pragma unroll
    for (int i = 0; i < 32; i += 8)
        tile[ty + i][tx] = W[(size_t)(EMB + k0 + ty + i) * HID + j0 + tx];
    __syncthreads();
#pragma unroll
    for (int i = 0; i < 32; i += 8)
        WT[(((size_t)g * HID + j0 + ty + i) << 11) + k0 + tx] = tile[tx][ty + i];
}

// A3: init h buffer 0 with tag 0 and h0 values
__global__ void a3_init(const float* __restrict__ hidden, u64* __restrict__ hbuf) {
    int j = blockIdx.x * 256 + threadIdx.x;
    if (j < HID) hbuf[j] = (u64)__float_as_uint(hidden[j]);  // hi=tag 0
}

#define HLOAD(p) __hip_atomic_load((p), __ATOMIC_RELAXED, __HIP_MEMORY_SCOPE_SYSTEM)

// B: persistent recurrence. 256 WGs x 512 threads, weights register-resident.
// Exchange: tagged u64 (tag<<32|f32) mailbox in the MALL (R7: one coalesced
// 64B line store per block per step; FETCH confirms 1 refetch/line/step/XCD).
// R8 diagnosis: VALUBusy(29.4%) x 7440cyc/step = ~2187 VALU-cyc per SIMD per
// step = 4 waves/SIMD x ~550cyc -> the CP was packing 2 blocks/CU on 128 CUs
// (128 CUs idle). Since all resident waves are exchange-lockstepped at the
// same step, their compute bursts serialize on the SIMD (~2200cyc wall/step)
// and widen the publish spread. Fix: pad static LDS to ~88.6KB so only ONE
// block fits per CU -> 256 blocks spread over all 256 CUs, 2 waves/SIMD.
// Also: 4-gate quadrant butterfly (14 cross-lane ops vs 24) and publish
// stores issued first in the iteration.
__global__ __launch_bounds__(512, 2) void b_lstm(
    const int* __restrict__ seq, const float* __restrict__ cell,
    const float* __restrict__ P, const float* __restrict__ WT,
    u64* __restrict__ hbuf, float* __restrict__ hs, float* __restrict__ dout) {
    __shared__ float h_lds[HID];
    __shared__ int seq_lds[T_STEPS];
    __shared__ float h_pub[8];
    // R8: occupancy limiter. 25KB(live) + 64000B pad = ~88.6KB static LDS;
    // 2x88.6KB > 160KB/CU so at most 1 block/CU -> grid spreads to 256 CUs.
    __shared__ float pad_force[16000];
    const int tid = threadIdx.x;
    const int l = tid & 63;
    const int jl = tid >> 6;
    const int jglob = (blockIdx.x << 3) + jl;

    {   // keep the pad allocation alive without measurable cost
        float dummy = pad_force[tid & 63];
        asm volatile("" ::"v"(dummy));
    }

    for (int q = tid; q < T_STEPS; q += 512) seq_lds[q] = seq[q];

    // per-thread k-ownership: k = q*256 + 4*l + r  (q=0..7, r=0..3)
    float4 wreg[4][8];
#pragma unroll
    for (int g = 0; g < 4; ++g)
#pragma unroll
        for (int q = 0; q < 8; ++q)
            wreg[g][q] = *(const float4*)&WT[(((size_t)g * HID + jglob) << 11) + (q << 8) + (l << 2)];

    float c_reg = cell[jglob];
    float h_last = 0.f;
    __syncthreads();

    for (int s = 0; s < T_STEPS; ++s) {
        // publish step s FIRST (values gathered at the end-barrier of iter
        // s-1; for s=0 they come from a3_init). tid 0..7: one 64B line, ONE
        // instr. Store-ack drains at the staging barrier, fully overlapped
        // with the poll phase (>= 1 MALL RT anyway).
        if (s > 0) {
            if (tid < 8) {
                u64 pv = ((u64)(u32)s << 32) | (u64)__float_as_uint(h_pub[tid]);
                __hip_atomic_store(hbuf + ((size_t)(s & 1) << 11) + (blockIdx.x << 3) + tid,
                                   pv, __ATOMIC_RELAXED, __HIP_MEMORY_SCOPE_SYSTEM);
            } else if (tid < 16) {
                hs[((size_t)(s - 1) << 11) + (blockIdx.x << 3) + (tid - 8)] = h_pub[tid - 8];
            }
        }

        const int ch = seq_lds[s];
        const float4 xg = *(const float4*)(P + ((((size_t)ch << 11) + jglob) << 2));

        // stage h_s (tag==s) into LDS; thread tid owns h[tid+512m], m=0..3.
        // Polls hit local L2 (cheap) until the writer's write-through
        // invalidates the line; then one refetch brings the fresh value.
        const u64* src = hbuf + ((s & 1) << 11);
        const u32 target = (u32)s;
        for (;;) {
            u64 t0 = HLOAD(src + tid);
            u64 t1 = HLOAD(src + 512 + tid);
            u64 t2 = HLOAD(src + 1024 + tid);
            u64 t3 = HLOAD(src + 1536 + tid);
            u32 bad = ((u32)(t0 >> 32) ^ target) | ((u32)(t1 >> 32) ^ target) |
                      ((u32)(t2 >> 32) ^ target) | ((u32)(t3 >> 32) ^ target);
            if (bad == 0) {
                h_lds[tid]        = __uint_as_float((u32)t0);
                h_lds[512 + tid]  = __uint_as_float((u32)t1);
                h_lds[1024 + tid] = __uint_as_float((u32)t2);
                h_lds[1536 + tid] = __uint_as_float((u32)t3);
                break;
            }
            __builtin_amdgcn_s_sleep(1);
        }
        __syncthreads();

        float a0 = 0.f, a1 = 0.f, a2 = 0.f, a3 = 0.f;
#pragma unroll
        for (int q = 0; q < 8; ++q) {
            const float4 hv = *(const float4*)&h_lds[(q << 8) + (l << 2)];
            a0 = fmaf(wreg[0][q].x, hv.x, a0);
            a0 = fmaf(wreg[0][q].y, hv.y, a0);
            a0 = fmaf(wreg[0][q].z, hv.z, a0);
            a0 = fmaf(wreg[0][q].w, hv.w, a0);
            a1 = fmaf(wreg[1][q].x, hv.x, a1);
            a1 = fmaf(wreg[1][q].y, hv.y, a1);
            a1 = fmaf(wreg[1][q].z, hv.z, a1);
            a1 = fmaf(wreg[1][q].w, hv.w, a1);
            a2 = fmaf(wreg[2][q].x, hv.x, a2);
            a2 = fmaf(wreg[2][q].y, hv.y, a2);
            a2 = fmaf(wreg[2][q].z, hv.z, a2);
            a2 = fmaf(wreg[2][q].w, hv.w, a2);
            a3 = fmaf(wreg[3][q].x, hv.x, a3);
            a3 = fmaf(wreg[3][q].y, hv.y, a3);
            a3 = fmaf(wreg[3][q].z, hv.z, a3);
            a3 = fmaf(wreg[3][q].w, hv.w, a3);
        }
        // R8: 4-gate quadrant butterfly. Fold lanes ^32 for all four gates,
        // split gates across half-waves, fold ^16, split across quadrants,
        // then finish ^8..^1 on a single value. 14 cross-lane ops + 10 adds
        // (was 24 + 24). Quadrant q (lanes 16q..16q+15) ends with gate-q sum.
        a0 += __shfl_xor(a0, 32, 64);
        a1 += __shfl_xor(a1, 32, 64);
        a2 += __shfl_xor(a2, 32, 64);
        a3 += __shfl_xor(a3, 32, 64);
        float u0 = (l < 32) ? a0 : a2;
        float u1 = (l < 32) ? a1 : a3;
        u0 += __shfl_xor(u0, 16, 64);
        u1 += __shfl_xor(u1, 16, 64);
        float w = ((l & 16) == 0) ? u0 : u1;
        w += __shfl_xor(w, 8, 64);
        w += __shfl_xor(w, 4, 64);
        w += __shfl_xor(w, 2, 64);
        w += __shfl_xor(w, 1, 64);
        const float sf = __shfl(w, 0, 64);   // gate f sum
        const float si = __shfl(w, 16, 64);  // gate i sum
        const float so = __shfl(w, 32, 64);  // gate o sum
        const float sg = __shfl(w, 48, 64);  // gate g sum

        const float pf = sf + xg.x, pi = si + xg.y, po = so + xg.z, pg = sg + xg.w;
        const float f = sigm_f(pf);
        const float ii = sigm_f(pi);
        const float oo = sigm_f(po);
        const float gg = tanh_f(pg);
        c_reg = fmaf(f, c_reg, ii * gg);
        h_last = oo * tanh_f(c_reg);   // identical in every lane (broadcast sums)

        if (l == 0) h_pub[jl] = h_last;   // gather for next iter's publish
        __syncthreads();                  // orders h_pub for the publisher wave
    }
    // final publish of step T (values h_{T-1} trace) + finals
    if (tid < 8) {
        hs[((size_t)(T_STEPS - 1) << 11) + (blockIdx.x << 3) + tid] = h_pub[tid];
    }
    if (l == 0) {
        dout[(size_t)T_STEPS * NCH + jglob] = h_last;          // h_fin
        dout[(size_t)T_STEPS * NCH + HID + jglob] = c_reg;     // c_fin
    }
}

// C: out[t] = hs[t] @ Wout + bout. grid 256 (16 t per block), 256 threads.
__global__ __launch_bounds__(256) void c_out(
    const float* __restrict__ hs, const float* __restrict__ Wout,
    const float* __restrict__ bout, float* __restrict__ out) {
    __shared__ float hsl[16][NCH];
    const int tid = threadIdx.x;
    const int bt = blockIdx.x << 4;
    float acc[16];
#pragma unroll
    for (int q = 0; q < 16; ++q) acc[q] = 0.f;
    for (int kc = 0; kc < 8; ++kc) {
#pragma unroll
        for (int q = 0; q < 16; ++q)
            hsl[q][tid] = hs[(((size_t)(bt + q)) << 11) + (kc << 8) + tid];
        __syncthreads();
        for (int kk = 0; kk < 256; ++kk) {
            float w = Wout[(size_t)((kc << 8) + kk) * NCH + tid];
#pragma unroll
            for (int q = 0; q < 16; ++q) acc[q] = fmaf(hsl[q][kk], w, acc[q]);
        }
        __syncthreads();
    }
    const float bb = bout[tid];
#pragma unroll
    for (int q = 0; q < 16; ++q) out[(size_t)(bt + q) * NCH + tid] = acc[q] + bb;
}

extern "C" void kernel_launch(void* const* d_in, const int* in_sizes, int n_in,
                              void* d_out, int out_size, void* d_ws, size_t ws_size,
                              hipStream_t stream) {
    const int* seq = (const int*)d_in[0];
    const float* hidden = (const float*)d_in[1];
    const float* cell = (const float*)d_in[2];
    const float* emb = (const float*)d_in[3];
    const float* Wf = (const float*)d_in[4];
    const float* bf = (const float*)d_in[5];
    const float* Wi = (const float*)d_in[6];
    const float* bi = (const float*)d_in[7];
    const float* Wo = (const float*)d_in[8];
    const float* bo = (const float*)d_in[9];
    const float* Wc = (const float*)d_in[10];
    const float* bc = (const float*)d_in[11];
    const float* Wout = (const float*)d_in[12];
    const float* bout = (const float*)d_in[13];
    float* out = (float*)d_out;

    // ws layout (floats): hbuf(2*2048 u64 = 8192 f) | WT(16.78M) | P(2.10M) | hs(8.39M)
    float* wsf = (float*)d_ws;
    u64* hbuf = (u64*)d_ws;
    float* WT = wsf + 8192;
    float* P = WT + (size_t)4 * HID * HID;
    float* hs = P + (size_t)NCH * HID * 4;

    a1_proj<<<128, 256, 0, stream>>>(emb, Wf, bf, Wi, bi, Wo, bo, Wc, bc, P);
    a2_transpose<<<dim3(64, 64, 4), dim3(32, 8), 0, stream>>>(Wf, Wi, Wo, Wc, WT);
    a3_init<<<8, 256, 0, stream>>>(hidden, hbuf);
    b_lstm<<<256, 512, 0, stream>>>(seq, cell, P, WT, hbuf, hs, out);
    c_out<<<256, 256, 0, stream>>>(hs, Wout, bout, out);
}